// Round 7
// baseline (253.787 us; speedup 1.0000x reference)
//
#include <hip/hip_runtime.h>

#define RES    256
#define NPIX   (RES * RES)
#define NTRI   1000
#define EPSF   1e-8f
#define CPT    12            // coef dwords per triangle
#define NSTRIP 64            // x-strips of 4 px
#define NYB    16            // y-blocks of 16 px
#define NBIN   (NSTRIP * NYB)   // 1024 bins per image
#define CAP    1024          // list capacity per bin (>= NTRI, no overflow possible)
#define CHK    4             // chunks (waves) per bin in rasterize
#define LOG2E2 2.8853900817779268f   // 2*log2(e)

// coef (12 f32/tri): a0,b0,c0,a1,b1,c1,a2,b2,c2, ik, mn*ik, pad
//   edge_i(px,py)=a*px+b*py+c ; x2=fma(s,ik,-mn*ik) ; tanh = 1 - 2*rcp(1+exp2(x2))
// bins: cnt[b*NBIN + strip*NYB + yb], lists u16 tri indices, CAP each.
// Invariant: mn>0 only for full-grid-bbox tris (binned everywhere); else mn==0 so
// unbinned pixels contribute exactly 0, and binned-outside pixels give
// rcp(1+exp2(0))=0.5 -> fcnt-2*0.5 = 0 exactly (same fmaf tree as the minmax scan).

// ---------------------------------------------------------------------------
// Kernel A: one block per (batch, triangle). Project, coefficients, bbox,
// min/max over bbox pixels, write coef record, append tri to overlapped bins.
// Also grid-stride zeroes `out` (runs before rasterize in-stream).
// ---------------------------------------------------------------------------
__global__ __launch_bounds__(256) void tri_setup(
    const float* __restrict__ meshes, const float* __restrict__ Km,
    const int* __restrict__ midx, const float* __restrict__ cams,
    float* __restrict__ coef, int* __restrict__ cnt,
    unsigned short* __restrict__ lists, float* __restrict__ out, int nout)
{
    const int blk = blockIdx.x;
    const int b = blk / NTRI;
    const int t = blk - b * NTRI;

    // zero output image (first 512 blocks cover 131072 px)
    { const int g = blk * 256 + threadIdx.x; if (g < nout) out[g] = 0.0f; }

    const float* cam = cams + b * 12;
    float M[12];
#pragma unroll
    for (int i = 0; i < 3; ++i) {
        const float k0 = Km[i*3+0], k1 = Km[i*3+1], k2 = Km[i*3+2];
#pragma unroll
        for (int j = 0; j < 4; ++j)
            M[i*4+j] = k0*cam[j] + k1*cam[4+j] + k2*cam[8+j];
    }
    const int m = midx[b];
    const float* tv = meshes + ((size_t)m * NTRI + t) * 9;
    float vx[3], vy[3];
#pragma unroll
    for (int v = 0; v < 3; ++v) {
        const float X = tv[v*3+0], Y = tv[v*3+1], Z = tv[v*3+2];
        const float w = M[8]*X + M[9]*Y + M[10]*Z + M[11] + EPSF;
        vx[v] = (M[0]*X + M[1]*Y + M[2]*Z + M[3]) / w;
        vy[v] = (M[4]*X + M[5]*Y + M[6]*Z + M[7]) / w;
    }

    const float e0x = vx[1]-vx[0], e0y = vy[1]-vy[0];
    const float e1x = vx[2]-vx[1], e1y = vy[2]-vy[1];
    const float e2x = vx[0]-vx[2], e2y = vy[0]-vy[2];
    const float N = e0x*e2y - e0y*e2x + EPSF;

    const float a0 = N*e0y, b0 = -N*e0x, c0 = N*(e0x*vy[0] - e0y*vx[0]);
    const float a1 = N*e1y, b1 = -N*e1x, c1 = N*(e1x*vy[1] - e1y*vx[1]);
    const float a2 = N*e2y, b2 = -N*e2x, c2 = N*(e2x*vy[2] - e2y*vx[2]);

    float mnx = fminf(fminf(vx[0],vx[1]),vx[2]);
    float mxx = fmaxf(fmaxf(vx[0],vx[1]),vx[2]);
    float mny = fminf(fminf(vy[0],vy[1]),vy[2]);
    float mxy = fmaxf(fmaxf(vy[0],vy[1]),vy[2]);
    mnx = fmaxf(fminf(mnx, 1e6f), -1e6f);  mxx = fmaxf(fminf(mxx, 1e6f), -1e6f);
    mny = fmaxf(fminf(mny, 1e6f), -1e6f);  mxy = fmaxf(fminf(mxy, 1e6f), -1e6f);
    const int bx0 = max(0,     (int)floorf(mnx) - 1);
    const int bx1 = min(RES-1, (int)ceilf (mxx) + 1);
    const int by0 = max(0,     (int)floorf(mny) - 1);
    const int by1 = min(RES-1, (int)ceilf (mxy) + 1);
    const bool empty = (bx0 > bx1) || (by0 > by1);

    float mn = INFINITY, mx = -INFINITY;
    if (!empty) {
        const int h = by1 - by0 + 1;
        int sh = 0;
        while ((1 << sh) < h) ++sh;
        const int hp = 1 << sh;
        const int area = (bx1 - bx0 + 1) << sh;
        for (int p = threadIdx.x; p < area; p += 256) {
            const int x = bx0 + (p >> sh);
            const int y = by0 + (p & (hp - 1));
            if (y <= by1) {
                const float fx = (float)x, fy = (float)y;
                const float t1 = fmaxf(fmaf(a0, fx, fmaf(b0, fy, c0)), 0.0f);
                const float t2 = fmaxf(fmaf(a1, fx, fmaf(b1, fy, c1)), 0.0f);
                const float t3 = fmaxf(fmaf(a2, fx, fmaf(b2, fy, c2)), 0.0f);
                const float s = t1 * t2 * t3;
                mn = fminf(mn, s);
                mx = fmaxf(mx, s);
            }
        }
    }
#pragma unroll
    for (int off = 32; off > 0; off >>= 1) {
        mn = fminf(mn, __shfl_down(mn, off, 64));
        mx = fmaxf(mx, __shfl_down(mx, off, 64));
    }
    __shared__ float smn[4], smx[4];
    const int lane = threadIdx.x & 63, wv = threadIdx.x >> 6;
    if (lane == 0) { smn[wv] = mn; smx[wv] = mx; }
    __syncthreads();
    if (threadIdx.x == 0) {
        mn = fminf(fminf(smn[0], smn[1]), fminf(smn[2], smn[3]));
        mx = fmaxf(fmaxf(smx[0], smx[1]), fmaxf(smx[2], smx[3]));
        if (empty) { mn = 0.0f; mx = 0.0f; }
        const bool fullgrid = (bx0 == 0 && bx1 == RES-1 && by0 == 0 && by1 == RES-1);
        if (!fullgrid) mn = 0.0f;   // some grid pixel strictly outside => s==0 there
        const float ik = LOG2E2 / (mx - mn + EPSF);
        float* r = coef + ((size_t)b * NTRI + t) * CPT;
        r[0]=a0; r[1]=b0; r[2]=c0; r[3]=a1; r[4]=b1; r[5]=c1;
        r[6]=a2; r[7]=b2; r[8]=c2;
        r[9]=ik; r[10]=mn*ik; r[11]=0.0f;
    }
    __syncthreads();   // smn/smx reuse barrier not needed; keeps bbox regs live-simple

    // bin append: thread s (0..63) handles x-strip s
    if (!empty && threadIdx.x < NSTRIP) {
        const int s = threadIdx.x;
        if (s >= (bx0 >> 2) && s <= (bx1 >> 2)) {
            const int yb0 = by0 >> 4, yb1 = by1 >> 4;
            for (int yb = yb0; yb <= yb1; ++yb) {
                const int bin = (b * NSTRIP + s) * NYB + yb;
                const int pos = atomicAdd(&cnt[bin], 1);
                lists[(size_t)bin * CAP + pos] = (unsigned short)t;
            }
        }
    }
}

// ---------------------------------------------------------------------------
// Kernel B: wave = one (bin, chunk). Bin = 4 cols x 16 rows = 64 px, 1 px/lane.
// Dense list walk, software-pipelined uniform loads, no divergent skips.
// ---------------------------------------------------------------------------
__global__ __launch_bounds__(256) void rasterize(
    const float* __restrict__ coef, const int* __restrict__ cnt,
    const unsigned short* __restrict__ lists, float* __restrict__ out)
{
    const int item  = blockIdx.x * 4 + (threadIdx.x >> 6);
    const int bin   = item >> 2;          // CHK = 4
    const int chunk = item & 3;
    const int b     = bin >> 10;          // NBIN = 1024
    const int rest  = bin & (NBIN - 1);
    const int strip = rest >> 4;
    const int yb    = rest & (NYB - 1);
    const int l     = threadIdx.x & 63;
    const int x     = (strip << 2) + (l >> 4);
    const int y     = (yb << 4) + (l & 15);
    const float fx  = (float)x, fy = (float)y;

    const int n = cnt[bin];
    const unsigned short* lp = lists + (size_t)bin * CAP;
    const float* cb = coef + (size_t)b * NTRI * CPT;

    float acc = 0.0f, fcnt = 0.0f;

    int i = chunk;
    if (i < n) {
        int t0 = lp[i];
        float r[CPT];
        {
            const float* rp = cb + t0 * CPT;
#pragma unroll
            for (int k = 0; k < CPT; ++k) r[k] = rp[k];
        }
        while (true) {
            const int inx = i + CHK;
            const bool more = inx < n;
            // prefetch next entry (fallback to current idx keeps load unconditional)
            const int t1 = more ? (int)lp[inx] : t0;
            float rn[CPT];
            {
                const float* rp = cb + t1 * CPT;
#pragma unroll
                for (int k = 0; k < CPT; ++k) rn[k] = rp[k];
            }
            // compute current
            const float u1 = fmaxf(fmaf(r[0], fx, fmaf(r[1], fy, r[2])), 0.0f);
            const float u2 = fmaxf(fmaf(r[3], fx, fmaf(r[4], fy, r[5])), 0.0f);
            const float u3 = fmaxf(fmaf(r[6], fx, fmaf(r[7], fy, r[8])), 0.0f);
            const float e  = __builtin_amdgcn_exp2f(fmaf(u1*u2*u3, r[9], -r[10]));
            acc  += __builtin_amdgcn_rcpf(1.0f + e);
            fcnt += 1.0f;
            if (!more) break;
#pragma unroll
            for (int k = 0; k < CPT; ++k) r[k] = rn[k];
            t0 = t1;
            i = inx;
        }
    }
    atomicAdd(out + (size_t)b * NPIX + (size_t)x * RES + y, fmaf(-2.0f, acc, fcnt));
}

extern "C" void kernel_launch(void* const* d_in, const int* in_sizes, int n_in,
                              void* d_out, int out_size, void* d_ws, size_t ws_size,
                              hipStream_t stream)
{
    const float* meshes = (const float*)d_in[0];
    const float* Km     = (const float*)d_in[1];
    const int*   midx   = (const int*)d_in[2];
    const float* cams   = (const float*)d_in[3];
    float* out = (float*)d_out;

    const int batch = in_sizes[3] / 12;     // camera_poses is (B,3,4)

    // ws layout: coef | cnt | lists
    float* coef = (float*)d_ws;
    size_t coef_bytes = (size_t)batch * NTRI * CPT * sizeof(float);
    int* cnt = (int*)((char*)d_ws + coef_bytes);
    size_t cnt_bytes = (size_t)batch * NBIN * sizeof(int);
    unsigned short* lists = (unsigned short*)((char*)cnt + cnt_bytes);

    hipMemsetAsync(cnt, 0, cnt_bytes, stream);
    tri_setup<<<dim3(batch * NTRI), dim3(256), 0, stream>>>(
        meshes, Km, midx, cams, coef, cnt, lists, out, batch * NPIX);
    rasterize<<<dim3(batch * NBIN), dim3(256), 0, stream>>>(coef, cnt, lists, out);
}

// Round 10
// 149.329 us; speedup vs baseline: 1.6995x; 1.6995x over previous
//
#include <hip/hip_runtime.h>

#define RES    256
#define NPIX   (RES * RES)
#define NTRI   1000
#define EPSF   1e-8f
#define CPT    12            // coef dwords per triangle
#define NCHK   4             // triangle chunks per tile
#define TPC    250           // tris per chunk
#define LOG2E2 2.8853900817779268f   // 2*log2(e)

// coef (12 f32/tri): a0,b0,c0,a1,b1,c1,a2,b2,c2, ik, mn*ik, pad
//   edge_i(px,py)=a*px+b*py+c ; x2=fma(s,ik,-mn*ik) ; tanh = 1 - 2*rcp(1+exp2(x2))
// bbox (1 u32/tri): bx0 | bx1<<8 | by0<<16 | by1<<24 ; empty = 0x00FF00FF
//   (bx1<bx0 can never overlap any tile -> always skipped)
// Invariant: mn>0 only for full-grid-bbox tris (hit every tile); otherwise mn==0,
// so skipped pixels contribute exactly 0 and hit-but-outside pixels give
// rcp(1+exp2(0))=0.5 -> fcnt-2*0.5=0 exactly (same fmaf tree as minmax scan).

// ---------------------------------------------------------------------------
// Kernel A: one block per (batch, triangle). Project, coefficients, bbox,
// min/max over bbox pixels, write coef record + packed bbox word.
// Also grid-stride zeroes `out` (rasterize runs after us in-stream).
// ---------------------------------------------------------------------------
__global__ __launch_bounds__(256) void tri_setup(
    const float* __restrict__ meshes, const float* __restrict__ Km,
    const int* __restrict__ midx, const float* __restrict__ cams,
    float* __restrict__ coef, unsigned int* __restrict__ bbox,
    float* __restrict__ out, int nout)
{
    const int blk = blockIdx.x;
    const int b = blk / NTRI;
    const int t = blk - b * NTRI;

    // zero output image (first 512 blocks cover 131072 px)
    { const int g = blk * 256 + threadIdx.x; if (g < nout) out[g] = 0.0f; }

    const float* cam = cams + b * 12;
    float M[12];
#pragma unroll
    for (int i = 0; i < 3; ++i) {
        const float k0 = Km[i*3+0], k1 = Km[i*3+1], k2 = Km[i*3+2];
#pragma unroll
        for (int j = 0; j < 4; ++j)
            M[i*4+j] = k0*cam[j] + k1*cam[4+j] + k2*cam[8+j];
    }
    const int m = midx[b];
    const float* tv = meshes + ((size_t)m * NTRI + t) * 9;
    float vx[3], vy[3];
#pragma unroll
    for (int v = 0; v < 3; ++v) {
        const float X = tv[v*3+0], Y = tv[v*3+1], Z = tv[v*3+2];
        const float w = M[8]*X + M[9]*Y + M[10]*Z + M[11] + EPSF;
        vx[v] = (M[0]*X + M[1]*Y + M[2]*Z + M[3]) / w;
        vy[v] = (M[4]*X + M[5]*Y + M[6]*Z + M[7]) / w;
    }

    const float e0x = vx[1]-vx[0], e0y = vy[1]-vy[0];
    const float e1x = vx[2]-vx[1], e1y = vy[2]-vy[1];
    const float e2x = vx[0]-vx[2], e2y = vy[0]-vy[2];
    const float N = e0x*e2y - e0y*e2x + EPSF;

    const float a0 = N*e0y, b0 = -N*e0x, c0 = N*(e0x*vy[0] - e0y*vx[0]);
    const float a1 = N*e1y, b1 = -N*e1x, c1 = N*(e1x*vy[1] - e1y*vx[1]);
    const float a2 = N*e2y, b2 = -N*e2x, c2 = N*(e2x*vy[2] - e2y*vx[2]);

    float mnx = fminf(fminf(vx[0],vx[1]),vx[2]);
    float mxx = fmaxf(fmaxf(vx[0],vx[1]),vx[2]);
    float mny = fminf(fminf(vy[0],vy[1]),vy[2]);
    float mxy = fmaxf(fmaxf(vy[0],vy[1]),vy[2]);
    mnx = fmaxf(fminf(mnx, 1e6f), -1e6f);  mxx = fmaxf(fminf(mxx, 1e6f), -1e6f);
    mny = fmaxf(fminf(mny, 1e6f), -1e6f);  mxy = fmaxf(fminf(mxy, 1e6f), -1e6f);
    const int bx0 = max(0,     (int)floorf(mnx) - 1);
    const int bx1 = min(RES-1, (int)ceilf (mxx) + 1);
    const int by0 = max(0,     (int)floorf(mny) - 1);
    const int by1 = min(RES-1, (int)ceilf (mxy) + 1);
    const bool empty = (bx0 > bx1) || (by0 > by1);

    float mn = INFINITY, mx = -INFINITY;
    if (!empty) {
        const int h = by1 - by0 + 1;
        int sh = 0;
        while ((1 << sh) < h) ++sh;
        const int hp = 1 << sh;
        const int area = (bx1 - bx0 + 1) << sh;
        for (int p = threadIdx.x; p < area; p += 256) {
            const int x = bx0 + (p >> sh);
            const int y = by0 + (p & (hp - 1));
            if (y <= by1) {
                const float fx = (float)x, fy = (float)y;
                const float t1 = fmaxf(fmaf(a0, fx, fmaf(b0, fy, c0)), 0.0f);
                const float t2 = fmaxf(fmaf(a1, fx, fmaf(b1, fy, c1)), 0.0f);
                const float t3 = fmaxf(fmaf(a2, fx, fmaf(b2, fy, c2)), 0.0f);
                const float s = t1 * t2 * t3;
                mn = fminf(mn, s);
                mx = fmaxf(mx, s);
            }
        }
    }
#pragma unroll
    for (int off = 32; off > 0; off >>= 1) {
        mn = fminf(mn, __shfl_down(mn, off, 64));
        mx = fmaxf(mx, __shfl_down(mx, off, 64));
    }
    __shared__ float smn[4], smx[4];
    const int lane = threadIdx.x & 63, wv = threadIdx.x >> 6;
    if (lane == 0) { smn[wv] = mn; smx[wv] = mx; }
    __syncthreads();
    if (threadIdx.x == 0) {
        mn = fminf(fminf(smn[0], smn[1]), fminf(smn[2], smn[3]));
        mx = fmaxf(fmaxf(smx[0], smx[1]), fmaxf(smx[2], smx[3]));
        if (empty) { mn = 0.0f; mx = 0.0f; }
        const bool fullgrid = (bx0 == 0 && bx1 == RES-1 && by0 == 0 && by1 == RES-1);
        if (!fullgrid) mn = 0.0f;   // some grid pixel strictly outside => s==0 there
        const float ik = LOG2E2 / (mx - mn + EPSF);
        float* r = coef + ((size_t)b * NTRI + t) * CPT;
        r[0]=a0; r[1]=b0; r[2]=c0; r[3]=a1; r[4]=b1; r[5]=c1;
        r[6]=a2; r[7]=b2; r[8]=c2;
        r[9]=ik; r[10]=mn*ik; r[11]=0.0f;
        bbox[(size_t)b * NTRI + t] = empty ? 0x00FF00FFu
            : ((unsigned)bx0 | ((unsigned)bx1 << 8) |
               ((unsigned)by0 << 16) | ((unsigned)by1 << 24));
    }
}

// ---------------------------------------------------------------------------
// Kernel B: wave = one (8x8 px tile, 250-tri chunk). Lanes load 4 coalesced
// bbox words -> 4 ballot masks (SGPR). Survivor walk is scalar-ALU bit
// extraction + wave-uniform s_load of the 12-dword coef record. 8192 waves,
// low VGPR -> deep occupancy hides the scalar-load latency.
// ---------------------------------------------------------------------------
__global__ __launch_bounds__(256) void rasterize(
    const float* __restrict__ coef, const unsigned int* __restrict__ bbox,
    float* __restrict__ out)
{
    const int wave_id = blockIdx.x * 4 + (threadIdx.x >> 6);
    const int chunk = wave_id & (NCHK - 1);
    const int tile  = (wave_id >> 2) & 1023;   // 32x32 tiles of 8x8 px
    const int b     = wave_id >> 12;
    const int tx0   = (tile >> 5) << 3;
    const int ty0   = (tile & 31) << 3;

    const int l  = threadIdx.x & 63;
    const int px = tx0 + (l >> 3);
    const int py = ty0 + (l & 7);
    const float fx = (float)px, fy = (float)py;

    const int base = chunk * TPC;
    const unsigned int* bbp = bbox + (size_t)b * NTRI + base;

    // load up to 4 coalesced bbox words per lane, test, ballot
    unsigned long long msk[4];
#pragma unroll
    for (int g = 0; g < 4; ++g) {
        const int idx = g * 64 + l;
        bool hit = false;
        if (idx < TPC) {
            const unsigned int w = bbp[idx];
            const int tbx0 = w & 255, tbx1 = (w >> 8) & 255;
            const int tby0 = (w >> 16) & 255, tby1 = w >> 24;
            hit = !(tbx1 < tx0 || tbx0 > tx0 + 7 || tby1 < ty0 || tby0 > ty0 + 7);
        }
        msk[g] = __ballot(hit);
    }

    float acc = 0.0f, fcnt = 0.0f;
    const float* cb = coef + ((size_t)b * NTRI + base) * CPT;

#pragma unroll
    for (int g = 0; g < 4; ++g) {
        unsigned long long m = msk[g];
        while (m) {
            const int bit = __builtin_ctzll(m);
            m &= m - 1;
            const float* r = cb + (g * 64 + bit) * CPT;
            const float u1 = fmaxf(fmaf(r[0], fx, fmaf(r[1], fy, r[2])), 0.0f);
            const float u2 = fmaxf(fmaf(r[3], fx, fmaf(r[4], fy, r[5])), 0.0f);
            const float u3 = fmaxf(fmaf(r[6], fx, fmaf(r[7], fy, r[8])), 0.0f);
            const float e  = __builtin_amdgcn_exp2f(fmaf(u1*u2*u3, r[9], -r[10]));
            acc  += __builtin_amdgcn_rcpf(1.0f + e);
            fcnt += 1.0f;
        }
    }

    atomicAdd(out + (size_t)b * NPIX + (size_t)px * RES + py,
              fmaf(-2.0f, acc, fcnt));
}

extern "C" void kernel_launch(void* const* d_in, const int* in_sizes, int n_in,
                              void* d_out, int out_size, void* d_ws, size_t ws_size,
                              hipStream_t stream)
{
    const float* meshes = (const float*)d_in[0];
    const float* Km     = (const float*)d_in[1];
    const int*   midx   = (const int*)d_in[2];
    const float* cams   = (const float*)d_in[3];
    float* out = (float*)d_out;

    const int batch = in_sizes[3] / 12;     // camera_poses is (B,3,4)

    float* coef = (float*)d_ws;                               // batch*1000*12 f32
    unsigned int* bbox =
        (unsigned int*)((char*)d_ws + (size_t)batch * NTRI * CPT * sizeof(float));

    tri_setup<<<dim3(batch * NTRI), dim3(256), 0, stream>>>(
        meshes, Km, midx, cams, coef, bbox, out, batch * NPIX);
    // waves = batch * 1024 tiles * NCHK chunks; 4 waves per block
    rasterize<<<dim3(batch * 1024 * NCHK / 4), dim3(256), 0, stream>>>(
        coef, bbox, out);
}

// Round 11
// 130.915 us; speedup vs baseline: 1.9386x; 1.1407x over previous
//
#include <hip/hip_runtime.h>

#define RES    256
#define NPIX   (RES * RES)
#define NTRI   1000
#define EPSF   1e-8f
#define CPT    12            // coef dwords per triangle
#define TPC    250           // tris per chunk (4 chunks = 4 waves per block)
#define LOG2E2 2.8853900817779268f   // 2*log2(e)

// coef (12 f32/tri): a0,b0,c0,a1,b1,c1,a2,b2,c2, ik, mn*ik, pad
//   edge_i(px,py)=a*px+b*py+c ; x2=fma(s,ik,-mn*ik) ; tanh = 1 - 2*rcp(1+exp2(x2))
// bbox (1 u32/tri): bx0 | bx1<<8 | by0<<16 | by1<<24 ; empty = 0x00FF00FF
// Invariant: mn>0 only for full-grid-bbox tris (hit every tile); otherwise mn==0,
// so culled pixels contribute exactly 0 and hit-but-outside pixels give
// rcp(1+exp2(0))=0.5 -> fcnt-2*0.5=0 exactly (same fmaf tree as minmax scan).

// ---------------------------------------------------------------------------
// Kernel A: one block per (batch, triangle). Project, coefficients, bbox,
// min/max of score over bbox pixels, write coef record + packed bbox word.
// (No output zeroing needed: rasterize writes every pixel with plain stores.)
// ---------------------------------------------------------------------------
__global__ __launch_bounds__(256) void tri_setup(
    const float* __restrict__ meshes, const float* __restrict__ Km,
    const int* __restrict__ midx, const float* __restrict__ cams,
    float* __restrict__ coef, unsigned int* __restrict__ bbox)
{
    const int blk = blockIdx.x;
    const int b = blk / NTRI;
    const int t = blk - b * NTRI;

    const float* cam = cams + b * 12;
    float M[12];
#pragma unroll
    for (int i = 0; i < 3; ++i) {
        const float k0 = Km[i*3+0], k1 = Km[i*3+1], k2 = Km[i*3+2];
#pragma unroll
        for (int j = 0; j < 4; ++j)
            M[i*4+j] = k0*cam[j] + k1*cam[4+j] + k2*cam[8+j];
    }
    const int m = midx[b];
    const float* tv = meshes + ((size_t)m * NTRI + t) * 9;
    float vx[3], vy[3];
#pragma unroll
    for (int v = 0; v < 3; ++v) {
        const float X = tv[v*3+0], Y = tv[v*3+1], Z = tv[v*3+2];
        const float w = M[8]*X + M[9]*Y + M[10]*Z + M[11] + EPSF;
        vx[v] = (M[0]*X + M[1]*Y + M[2]*Z + M[3]) / w;
        vy[v] = (M[4]*X + M[5]*Y + M[6]*Z + M[7]) / w;
    }

    const float e0x = vx[1]-vx[0], e0y = vy[1]-vy[0];
    const float e1x = vx[2]-vx[1], e1y = vy[2]-vy[1];
    const float e2x = vx[0]-vx[2], e2y = vy[0]-vy[2];
    const float N = e0x*e2y - e0y*e2x + EPSF;

    const float a0 = N*e0y, b0 = -N*e0x, c0 = N*(e0x*vy[0] - e0y*vx[0]);
    const float a1 = N*e1y, b1 = -N*e1x, c1 = N*(e1x*vy[1] - e1y*vx[1]);
    const float a2 = N*e2y, b2 = -N*e2x, c2 = N*(e2x*vy[2] - e2y*vx[2]);

    float mnx = fminf(fminf(vx[0],vx[1]),vx[2]);
    float mxx = fmaxf(fmaxf(vx[0],vx[1]),vx[2]);
    float mny = fminf(fminf(vy[0],vy[1]),vy[2]);
    float mxy = fmaxf(fmaxf(vy[0],vy[1]),vy[2]);
    mnx = fmaxf(fminf(mnx, 1e6f), -1e6f);  mxx = fmaxf(fminf(mxx, 1e6f), -1e6f);
    mny = fmaxf(fminf(mny, 1e6f), -1e6f);  mxy = fmaxf(fminf(mxy, 1e6f), -1e6f);
    const int bx0 = max(0,     (int)floorf(mnx) - 1);
    const int bx1 = min(RES-1, (int)ceilf (mxx) + 1);
    const int by0 = max(0,     (int)floorf(mny) - 1);
    const int by1 = min(RES-1, (int)ceilf (mxy) + 1);
    const bool empty = (bx0 > bx1) || (by0 > by1);

    float mn = INFINITY, mx = -INFINITY;
    if (!empty) {
        const int h = by1 - by0 + 1;
        int sh = 0;
        while ((1 << sh) < h) ++sh;
        const int hp = 1 << sh;
        const int area = (bx1 - bx0 + 1) << sh;
        for (int p = threadIdx.x; p < area; p += 256) {
            const int x = bx0 + (p >> sh);
            const int y = by0 + (p & (hp - 1));
            if (y <= by1) {
                const float fx = (float)x, fy = (float)y;
                const float t1 = fmaxf(fmaf(a0, fx, fmaf(b0, fy, c0)), 0.0f);
                const float t2 = fmaxf(fmaf(a1, fx, fmaf(b1, fy, c1)), 0.0f);
                const float t3 = fmaxf(fmaf(a2, fx, fmaf(b2, fy, c2)), 0.0f);
                const float s = t1 * t2 * t3;
                mn = fminf(mn, s);
                mx = fmaxf(mx, s);
            }
        }
    }
#pragma unroll
    for (int off = 32; off > 0; off >>= 1) {
        mn = fminf(mn, __shfl_down(mn, off, 64));
        mx = fmaxf(mx, __shfl_down(mx, off, 64));
    }
    __shared__ float smn[4], smx[4];
    const int lane = threadIdx.x & 63, wv = threadIdx.x >> 6;
    if (lane == 0) { smn[wv] = mn; smx[wv] = mx; }
    __syncthreads();
    if (threadIdx.x == 0) {
        mn = fminf(fminf(smn[0], smn[1]), fminf(smn[2], smn[3]));
        mx = fmaxf(fmaxf(smx[0], smx[1]), fmaxf(smx[2], smx[3]));
        if (empty) { mn = 0.0f; mx = 0.0f; }
        const bool fullgrid = (bx0 == 0 && bx1 == RES-1 && by0 == 0 && by1 == RES-1);
        if (!fullgrid) mn = 0.0f;   // some grid pixel strictly outside => s==0 there
        const float ik = LOG2E2 / (mx - mn + EPSF);
        float* r = coef + ((size_t)b * NTRI + t) * CPT;
        r[0]=a0; r[1]=b0; r[2]=c0; r[3]=a1; r[4]=b1; r[5]=c1;
        r[6]=a2; r[7]=b2; r[8]=c2;
        r[9]=ik; r[10]=mn*ik; r[11]=0.0f;
        bbox[(size_t)b * NTRI + t] = empty ? 0x00FF00FFu
            : ((unsigned)bx0 | ((unsigned)bx1 << 8) |
               ((unsigned)by0 << 16) | ((unsigned)by1 << 24));
    }
}

// ---------------------------------------------------------------------------
// Kernel B: block = one (batch, 8x8 px tile); 4 waves = 4 chunks of 250 tris.
// All 1000 coef records staged in LDS once per block (48KB). Per chunk:
// coalesced bbox loads -> ballot masks; survivor walk reads wave-uniform
// (broadcast) LDS records. Cross-wave LDS reduce, plain store (no atomics).
// ---------------------------------------------------------------------------
__global__ __launch_bounds__(256) void rasterize(
    const float* __restrict__ coef, const unsigned int* __restrict__ bbox,
    float* __restrict__ out)
{
    __shared__ float cl[NTRI * CPT];   // 48 KB
    __shared__ float red[3][64];

    const int blk  = blockIdx.x;
    const int b    = blk >> 10;
    const int tile = blk & 1023;           // 32x32 tiles of 8x8 px
    const int tx0  = (tile >> 5) << 3;
    const int ty0  = (tile & 31) << 3;

    // stage all coef records for this batch
    {
        const float4* src = (const float4*)(coef + (size_t)b * NTRI * CPT);
        float4* dst = (float4*)cl;
        for (int i = threadIdx.x; i < NTRI * CPT / 4; i += 256) dst[i] = src[i];
    }
    __syncthreads();

    const int wv = threadIdx.x >> 6;       // chunk id
    const int l  = threadIdx.x & 63;
    const int px = tx0 + (l >> 3);
    const int py = ty0 + (l & 7);
    const float fx = (float)px, fy = (float)py;

    const int base = wv * TPC;
    const unsigned int* bbp = bbox + (size_t)b * NTRI + base;

    unsigned long long msk[4];
#pragma unroll
    for (int g = 0; g < 4; ++g) {
        const int idx = g * 64 + l;
        bool hit = false;
        if (idx < TPC) {
            const unsigned int w = bbp[idx];
            const int tbx0 = w & 255, tbx1 = (w >> 8) & 255;
            const int tby0 = (w >> 16) & 255, tby1 = w >> 24;
            hit = !(tbx1 < tx0 || tbx0 > tx0 + 7 || tby1 < ty0 || tby0 > ty0 + 7);
        }
        msk[g] = __ballot(hit);
    }

    float acc = 0.0f, fcnt = 0.0f;
#pragma unroll
    for (int g = 0; g < 4; ++g) {
        unsigned long long m = msk[g];
        while (m) {
            const int bit = __builtin_ctzll(m);
            m &= m - 1;
            const float* r = &cl[(base + g * 64 + bit) * CPT];
            const float u1 = fmaxf(fmaf(r[0], fx, fmaf(r[1], fy, r[2])), 0.0f);
            const float u2 = fmaxf(fmaf(r[3], fx, fmaf(r[4], fy, r[5])), 0.0f);
            const float u3 = fmaxf(fmaf(r[6], fx, fmaf(r[7], fy, r[8])), 0.0f);
            const float e  = __builtin_amdgcn_exp2f(fmaf(u1*u2*u3, r[9], -r[10]));
            acc  += __builtin_amdgcn_rcpf(1.0f + e);
            fcnt += 1.0f;
        }
    }

    float v = fmaf(-2.0f, acc, fcnt);
    if (wv != 0) red[wv - 1][l] = v;
    __syncthreads();
    if (wv == 0) {
        v += red[0][l] + red[1][l] + red[2][l];
        out[(size_t)b * NPIX + (size_t)px * RES + py] = v;
    }
}

extern "C" void kernel_launch(void* const* d_in, const int* in_sizes, int n_in,
                              void* d_out, int out_size, void* d_ws, size_t ws_size,
                              hipStream_t stream)
{
    const float* meshes = (const float*)d_in[0];
    const float* Km     = (const float*)d_in[1];
    const int*   midx   = (const int*)d_in[2];
    const float* cams   = (const float*)d_in[3];
    float* out = (float*)d_out;

    const int batch = in_sizes[3] / 12;     // camera_poses is (B,3,4)

    float* coef = (float*)d_ws;                               // batch*1000*12 f32
    unsigned int* bbox =
        (unsigned int*)((char*)d_ws + (size_t)batch * NTRI * CPT * sizeof(float));

    tri_setup<<<dim3(batch * NTRI), dim3(256), 0, stream>>>(
        meshes, Km, midx, cams, coef, bbox);
    rasterize<<<dim3(batch * 1024), dim3(256), 0, stream>>>(coef, bbox, out);
}

// Round 12
// 115.847 us; speedup vs baseline: 2.1907x; 1.1301x over previous
//
#include <hip/hip_runtime.h>

#define RES    256
#define NPIX   (RES * RES)
#define NTRI   1000
#define EPSF   1e-8f
#define CPT    12            // coef dwords per triangle
#define NCHK   4             // chunks per tile (separate blocks)
#define TPC    250           // tris per chunk
#define LOG2E2 2.8853900817779268f   // 2*log2(e)

// coef (12 f32/tri): a0,b0,c0,a1,b1,c1,a2,b2,c2, ik, mn*ik, pad
//   edge_i(px,py)=a*px+b*py+c ; x2=fma(s,ik,-mn*ik) ; tanh = 1 - 2*rcp(1+exp2(x2))
// bbox (1 u32/tri): bx0 | bx1<<8 | by0<<16 | by1<<24 ; empty = 0x00FF00FF
// Invariant: mn>0 only for full-grid-bbox tris (hit every tile); otherwise mn==0,
// so culled pixels contribute exactly 0 and hit-but-outside pixels give
// rcp(1+exp2(0))=0.5 -> fcnt-2*0.5=0 exactly (same fmaf tree as minmax scan).

// ---------------------------------------------------------------------------
// Kernel A: one block per (batch, triangle). Project, coefficients, bbox,
// min/max of score over bbox pixels, write coef record + packed bbox word.
// Also grid-stride zeroes `out` (rasterize atomicAdds per chunk).
// ---------------------------------------------------------------------------
__global__ __launch_bounds__(256) void tri_setup(
    const float* __restrict__ meshes, const float* __restrict__ Km,
    const int* __restrict__ midx, const float* __restrict__ cams,
    float* __restrict__ coef, unsigned int* __restrict__ bbox,
    float* __restrict__ out, int nout)
{
    const int blk = blockIdx.x;
    const int b = blk / NTRI;
    const int t = blk - b * NTRI;

    { const int g = blk * 256 + threadIdx.x; if (g < nout) out[g] = 0.0f; }

    const float* cam = cams + b * 12;
    float M[12];
#pragma unroll
    for (int i = 0; i < 3; ++i) {
        const float k0 = Km[i*3+0], k1 = Km[i*3+1], k2 = Km[i*3+2];
#pragma unroll
        for (int j = 0; j < 4; ++j)
            M[i*4+j] = k0*cam[j] + k1*cam[4+j] + k2*cam[8+j];
    }
    const int m = midx[b];
    const float* tv = meshes + ((size_t)m * NTRI + t) * 9;
    float vx[3], vy[3];
#pragma unroll
    for (int v = 0; v < 3; ++v) {
        const float X = tv[v*3+0], Y = tv[v*3+1], Z = tv[v*3+2];
        const float w = M[8]*X + M[9]*Y + M[10]*Z + M[11] + EPSF;
        vx[v] = (M[0]*X + M[1]*Y + M[2]*Z + M[3]) / w;
        vy[v] = (M[4]*X + M[5]*Y + M[6]*Z + M[7]) / w;
    }

    const float e0x = vx[1]-vx[0], e0y = vy[1]-vy[0];
    const float e1x = vx[2]-vx[1], e1y = vy[2]-vy[1];
    const float e2x = vx[0]-vx[2], e2y = vy[0]-vy[2];
    const float N = e0x*e2y - e0y*e2x + EPSF;

    const float a0 = N*e0y, b0 = -N*e0x, c0 = N*(e0x*vy[0] - e0y*vx[0]);
    const float a1 = N*e1y, b1 = -N*e1x, c1 = N*(e1x*vy[1] - e1y*vx[1]);
    const float a2 = N*e2y, b2 = -N*e2x, c2 = N*(e2x*vy[2] - e2y*vx[2]);

    float mnx = fminf(fminf(vx[0],vx[1]),vx[2]);
    float mxx = fmaxf(fmaxf(vx[0],vx[1]),vx[2]);
    float mny = fminf(fminf(vy[0],vy[1]),vy[2]);
    float mxy = fmaxf(fmaxf(vy[0],vy[1]),vy[2]);
    mnx = fmaxf(fminf(mnx, 1e6f), -1e6f);  mxx = fmaxf(fminf(mxx, 1e6f), -1e6f);
    mny = fmaxf(fminf(mny, 1e6f), -1e6f);  mxy = fmaxf(fminf(mxy, 1e6f), -1e6f);
    const int bx0 = max(0,     (int)floorf(mnx) - 1);
    const int bx1 = min(RES-1, (int)ceilf (mxx) + 1);
    const int by0 = max(0,     (int)floorf(mny) - 1);
    const int by1 = min(RES-1, (int)ceilf (mxy) + 1);
    const bool empty = (bx0 > bx1) || (by0 > by1);

    float mn = INFINITY, mx = -INFINITY;
    if (!empty) {
        const int h = by1 - by0 + 1;
        int sh = 0;
        while ((1 << sh) < h) ++sh;
        const int hp = 1 << sh;
        const int area = (bx1 - bx0 + 1) << sh;
        for (int p = threadIdx.x; p < area; p += 256) {
            const int x = bx0 + (p >> sh);
            const int y = by0 + (p & (hp - 1));
            if (y <= by1) {
                const float fx = (float)x, fy = (float)y;
                const float t1 = fmaxf(fmaf(a0, fx, fmaf(b0, fy, c0)), 0.0f);
                const float t2 = fmaxf(fmaf(a1, fx, fmaf(b1, fy, c1)), 0.0f);
                const float t3 = fmaxf(fmaf(a2, fx, fmaf(b2, fy, c2)), 0.0f);
                const float s = t1 * t2 * t3;
                mn = fminf(mn, s);
                mx = fmaxf(mx, s);
            }
        }
    }
#pragma unroll
    for (int off = 32; off > 0; off >>= 1) {
        mn = fminf(mn, __shfl_down(mn, off, 64));
        mx = fmaxf(mx, __shfl_down(mx, off, 64));
    }
    __shared__ float smn[4], smx[4];
    const int lane = threadIdx.x & 63, wv = threadIdx.x >> 6;
    if (lane == 0) { smn[wv] = mn; smx[wv] = mx; }
    __syncthreads();
    if (threadIdx.x == 0) {
        mn = fminf(fminf(smn[0], smn[1]), fminf(smn[2], smn[3]));
        mx = fmaxf(fmaxf(smx[0], smx[1]), fmaxf(smx[2], smx[3]));
        if (empty) { mn = 0.0f; mx = 0.0f; }
        const bool fullgrid = (bx0 == 0 && bx1 == RES-1 && by0 == 0 && by1 == RES-1);
        if (!fullgrid) mn = 0.0f;   // some grid pixel strictly outside => s==0 there
        const float ik = LOG2E2 / (mx - mn + EPSF);
        float* r = coef + ((size_t)b * NTRI + t) * CPT;
        r[0]=a0; r[1]=b0; r[2]=c0; r[3]=a1; r[4]=b1; r[5]=c1;
        r[6]=a2; r[7]=b2; r[8]=c2;
        r[9]=ik; r[10]=mn*ik; r[11]=0.0f;
        bbox[(size_t)b * NTRI + t] = empty ? 0x00FF00FFu
            : ((unsigned)bx0 | ((unsigned)bx1 << 8) |
               ((unsigned)by0 << 16) | ((unsigned)by1 << 24));
    }
}

// ---------------------------------------------------------------------------
// Kernel B: block = one (batch, 16x16 tile, 250-tri chunk); 256 threads =
// 256 pixels. Phase 1: ballot-compact survivor indices into LDS list.
// Phase 2: stage survivor records into LDS (<=12KB). Phase 3: uniform
// broadcast walk of the list, every iteration serves all 256 pixels.
// atomicAdd per chunk into pre-zeroed out (distinct addresses).
// ---------------------------------------------------------------------------
__global__ __launch_bounds__(256) void rasterize(
    const float* __restrict__ coef, const unsigned int* __restrict__ bbox,
    float* __restrict__ out)
{
    __shared__ float cl[TPC * CPT];          // 12 KB worst case
    __shared__ unsigned short s_list[256];
    __shared__ int s_n, wbase[4];

    const int blk   = blockIdx.x;
    const int b     = blk >> 10;
    const int rest  = blk & 1023;
    const int chunk = rest & (NCHK - 1);     // chunk-major: heavy tiles spread
    const int tile  = rest >> 2;             // 16x16 tiles of 16x16 px
    const int tx0   = (tile >> 4) << 4;
    const int ty0   = (tile & 15) << 4;

    const int l  = threadIdx.x & 63;
    const int wv = threadIdx.x >> 6;

    if (threadIdx.x == 0) s_n = 0;
    __syncthreads();

    // phase 1: cull + compact
    const int base = chunk * TPC;
    const int t = threadIdx.x;
    bool hit = false;
    if (t < TPC) {
        const unsigned int w = bbox[(size_t)b * NTRI + base + t];
        const int tbx0 = w & 255, tbx1 = (w >> 8) & 255;
        const int tby0 = (w >> 16) & 255, tby1 = w >> 24;
        hit = !(tbx1 < tx0 || tbx0 > tx0 + 15 || tby1 < ty0 || tby0 > ty0 + 15);
    }
    const unsigned long long m = __ballot(hit);
    if (l == 0) wbase[wv] = atomicAdd(&s_n, (int)__popcll(m));
    __syncthreads();
    if (hit) {
        const int pos = wbase[wv] + (int)__popcll(m & ((1ull << l) - 1ull));
        s_list[pos] = (unsigned short)t;
    }
    __syncthreads();
    const int n = s_n;

    // phase 2: stage survivor records (12 dwords each), coalesced-ish gather
    {
        const float* cb = coef + ((size_t)b * NTRI + base) * CPT;
        for (int j = threadIdx.x; j < n * CPT; j += 256) {
            const int k = j / CPT, w = j - k * CPT;
            cl[j] = cb[(int)s_list[k] * CPT + w];
        }
    }
    __syncthreads();

    // phase 3: pixel-parallel eval, uniform broadcast walk
    const int px = tx0 + (threadIdx.x >> 4);
    const int py = ty0 + (threadIdx.x & 15);
    const float fx = (float)px, fy = (float)py;

    float acc = 0.0f;
#pragma unroll 2
    for (int k = 0; k < n; ++k) {
        const float* r = &cl[k * CPT];
        const float u1 = fmaxf(fmaf(r[0], fx, fmaf(r[1], fy, r[2])), 0.0f);
        const float u2 = fmaxf(fmaf(r[3], fx, fmaf(r[4], fy, r[5])), 0.0f);
        const float u3 = fmaxf(fmaf(r[6], fx, fmaf(r[7], fy, r[8])), 0.0f);
        const float e  = __builtin_amdgcn_exp2f(fmaf(u1*u2*u3, r[9], -r[10]));
        acc += __builtin_amdgcn_rcpf(1.0f + e);
    }

    const float v = fmaf(-2.0f, acc, (float)n);
    atomicAdd(out + (size_t)b * NPIX + (size_t)px * RES + py, v);
}

extern "C" void kernel_launch(void* const* d_in, const int* in_sizes, int n_in,
                              void* d_out, int out_size, void* d_ws, size_t ws_size,
                              hipStream_t stream)
{
    const float* meshes = (const float*)d_in[0];
    const float* Km     = (const float*)d_in[1];
    const int*   midx   = (const int*)d_in[2];
    const float* cams   = (const float*)d_in[3];
    float* out = (float*)d_out;

    const int batch = in_sizes[3] / 12;     // camera_poses is (B,3,4)

    float* coef = (float*)d_ws;                               // batch*1000*12 f32
    unsigned int* bbox =
        (unsigned int*)((char*)d_ws + (size_t)batch * NTRI * CPT * sizeof(float));

    tri_setup<<<dim3(batch * NTRI), dim3(256), 0, stream>>>(
        meshes, Km, midx, cams, coef, bbox, out, batch * NPIX);
    // blocks = batch * 256 tiles * 4 chunks
    rasterize<<<dim3(batch * 256 * NCHK), dim3(256), 0, stream>>>(coef, bbox, out);
}

// Round 13
// 90.928 us; speedup vs baseline: 2.7911x; 1.2741x over previous
//
#include <hip/hip_runtime.h>

#define RES    256
#define NPIX   (RES * RES)
#define NTRI   1000
#define EPSF   1e-8f
#define CPT    12            // coef dwords per triangle
#define NCHK   4             // chunks per tile (separate blocks)
#define TPC    250           // tris per chunk
#define LOG2E2 2.8853900817779268f   // 2*log2(e)

// coef (12 f32/tri): a0,b0,c0,a1,b1,c1,a2,b2,c2, ik, mn*ik, pad
//   edge_i(px,py)=a*px+b*py+c ; x2=fma(s,ik,-mn*ik) ; tanh = 1 - 2*rcp(1+exp2(x2))
// bbox (1 u32/tri): bx0 | bx1<<8 | by0<<16 | by1<<24 ; empty = 0x00FF00FF
//
// tri_setup math (no grid scan):
//  mn = min over the 4 grid corners. s is quasi-concave, so if any grid px is
//  outside the tri then some corner is outside (s=0 there = exact ref value);
//  if the grid is inside the tri, lattice min is at a hull corner.
//  mx = max over rows of the row max; per row s(x) is log-concave and zero at
//  the feasible endpoints, so the integer row max is adjacent to a root of
//  d/dx log s = 0 (a quadratic). Candidates: both roots (+neighbors) and the
//  bbox x-endpoints, all evaluated with the SAME fmaf tree rasterize uses.

// ---------------------------------------------------------------------------
// Kernel A: one block per (batch, triangle). Thread = one bbox row.
// ---------------------------------------------------------------------------
__global__ __launch_bounds__(256) void tri_setup(
    const float* __restrict__ meshes, const float* __restrict__ Km,
    const int* __restrict__ midx, const float* __restrict__ cams,
    float* __restrict__ coef, unsigned int* __restrict__ bbox,
    float* __restrict__ out, int nout)
{
    const int blk = blockIdx.x;
    const int b = blk / NTRI;
    const int t = blk - b * NTRI;

    { const int g = blk * 256 + threadIdx.x; if (g < nout) out[g] = 0.0f; }

    const float* cam = cams + b * 12;
    float M[12];
#pragma unroll
    for (int i = 0; i < 3; ++i) {
        const float k0 = Km[i*3+0], k1 = Km[i*3+1], k2 = Km[i*3+2];
#pragma unroll
        for (int j = 0; j < 4; ++j)
            M[i*4+j] = k0*cam[j] + k1*cam[4+j] + k2*cam[8+j];
    }
    const int m = midx[b];
    const float* tv = meshes + ((size_t)m * NTRI + t) * 9;
    float vx[3], vy[3];
#pragma unroll
    for (int v = 0; v < 3; ++v) {
        const float X = tv[v*3+0], Y = tv[v*3+1], Z = tv[v*3+2];
        const float w = M[8]*X + M[9]*Y + M[10]*Z + M[11] + EPSF;
        vx[v] = (M[0]*X + M[1]*Y + M[2]*Z + M[3]) / w;
        vy[v] = (M[4]*X + M[5]*Y + M[6]*Z + M[7]) / w;
    }

    const float e0x = vx[1]-vx[0], e0y = vy[1]-vy[0];
    const float e1x = vx[2]-vx[1], e1y = vy[2]-vy[1];
    const float e2x = vx[0]-vx[2], e2y = vy[0]-vy[2];
    const float N = e0x*e2y - e0y*e2x + EPSF;

    const float a0 = N*e0y, b0 = -N*e0x, c0 = N*(e0x*vy[0] - e0y*vx[0]);
    const float a1 = N*e1y, b1 = -N*e1x, c1 = N*(e1x*vy[1] - e1y*vx[1]);
    const float a2 = N*e2y, b2 = -N*e2x, c2 = N*(e2x*vy[2] - e2y*vx[2]);

    float mnx = fminf(fminf(vx[0],vx[1]),vx[2]);
    float mxx = fmaxf(fmaxf(vx[0],vx[1]),vx[2]);
    float mny = fminf(fminf(vy[0],vy[1]),vy[2]);
    float mxy = fmaxf(fmaxf(vy[0],vy[1]),vy[2]);
    mnx = fmaxf(fminf(mnx, 1e6f), -1e6f);  mxx = fmaxf(fminf(mxx, 1e6f), -1e6f);
    mny = fmaxf(fminf(mny, 1e6f), -1e6f);  mxy = fmaxf(fminf(mxy, 1e6f), -1e6f);
    const int bx0 = max(0,     (int)floorf(mnx) - 1);
    const int bx1 = min(RES-1, (int)ceilf (mxx) + 1);
    const int by0 = max(0,     (int)floorf(mny) - 1);
    const int by1 = min(RES-1, (int)ceilf (mxy) + 1);
    const bool empty = (bx0 > bx1) || (by0 > by1);

    // ---- per-row analytic max ----
    float rowmax = 0.0f;
    if (!empty && threadIdx.x <= (unsigned)(by1 - by0)) {
        const float fy = (float)(by0 + (int)threadIdx.x);
        const float B0 = fmaf(b0, fy, c0);
        const float B1 = fmaf(b1, fy, c1);
        const float B2 = fmaf(b2, fy, c2);

        // normalized quadratic for d/dx log s = 0 (roots invariant to scaling)
        const float l0 = 1.0f / (fabsf(a0) + fabsf(B0) + 1e-30f);
        const float l1 = 1.0f / (fabsf(a1) + fabsf(B1) + 1e-30f);
        const float l2 = 1.0f / (fabsf(a2) + fabsf(B2) + 1e-30f);
        const float n0 = a0*l0, p0 = B0*l0;
        const float n1 = a1*l1, p1 = B1*l1;
        const float n2 = a2*l2, p2 = B2*l2;
        const float qa = 3.0f * n0*n1*n2;
        const float qb = 2.0f * (n0*n1*p2 + n0*n2*p1 + n1*n2*p0);
        const float qc = n0*p1*p2 + n1*p0*p2 + n2*p0*p1;

        float x1, x2;
        if (fabsf(qa) > 1e-30f) {
            const float disc = qb*qb - 4.0f*qa*qc;
            if (disc >= 0.0f) {
                const float rt = sqrtf(disc);
                x1 = (-qb - rt) / (2.0f*qa);
                x2 = (-qb + rt) / (2.0f*qa);
            } else {
                x1 = x2 = -qb / (2.0f*qa);
            }
        } else if (fabsf(qb) > 1e-30f) {
            x1 = x2 = -qc / qb;
        } else {
            x1 = x2 = (float)bx0;
        }

        const int f1 = (int)floorf(x1), f2 = (int)floorf(x2);
        int cand[12] = { f1-1, f1, f1+1, f1+2,  f2-1, f2, f2+1, f2+2,
                         bx0, bx0+1, bx1-1, bx1 };
#pragma unroll
        for (int k = 0; k < 12; ++k) {
            const int xi = min(max(cand[k], bx0), bx1);
            const float fx = (float)xi;
            const float u1 = fmaxf(fmaf(a0, fx, B0), 0.0f);
            const float u2 = fmaxf(fmaf(a1, fx, B1), 0.0f);
            const float u3 = fmaxf(fmaf(a2, fx, B2), 0.0f);
            rowmax = fmaxf(rowmax, u1*u2*u3);
        }
    }

    // block max-reduce
#pragma unroll
    for (int off = 32; off > 0; off >>= 1)
        rowmax = fmaxf(rowmax, __shfl_down(rowmax, off, 64));
    __shared__ float smx[4];
    __shared__ float scorner[4];
    const int lane = threadIdx.x & 63, wv = threadIdx.x >> 6;
    if (lane == 0) smx[wv] = rowmax;

    // corners (threads 0..3) -> exact grid min
    if (threadIdx.x < 4) {
        const float fx = (threadIdx.x & 1) ? 255.0f : 0.0f;
        const float fy = (threadIdx.x & 2) ? 255.0f : 0.0f;
        const float u1 = fmaxf(fmaf(a0, fx, fmaf(b0, fy, c0)), 0.0f);
        const float u2 = fmaxf(fmaf(a1, fx, fmaf(b1, fy, c1)), 0.0f);
        const float u3 = fmaxf(fmaf(a2, fx, fmaf(b2, fy, c2)), 0.0f);
        scorner[threadIdx.x] = u1*u2*u3;
    }
    __syncthreads();

    if (threadIdx.x == 0) {
        const float mn = fminf(fminf(scorner[0], scorner[1]),
                               fminf(scorner[2], scorner[3]));
        float mx = fmaxf(fmaxf(smx[0], smx[1]), fmaxf(smx[2], smx[3]));
        mx = fmaxf(mx, mn);   // safety: mx >= mn
        const float ik = LOG2E2 / (mx - mn + EPSF);
        float* r = coef + ((size_t)b * NTRI + t) * CPT;
        r[0]=a0; r[1]=b0; r[2]=c0; r[3]=a1; r[4]=b1; r[5]=c1;
        r[6]=a2; r[7]=b2; r[8]=c2;
        r[9]=ik; r[10]=mn*ik; r[11]=0.0f;
        bbox[(size_t)b * NTRI + t] = empty ? 0x00FF00FFu
            : ((unsigned)bx0 | ((unsigned)bx1 << 8) |
               ((unsigned)by0 << 16) | ((unsigned)by1 << 24));
    }
}

// ---------------------------------------------------------------------------
// Kernel B (unchanged from R12): block = (batch, 16x16 tile, 250-tri chunk);
// ballot-compact survivors, stage survivor records to LDS, pixel-parallel walk.
// ---------------------------------------------------------------------------
__global__ __launch_bounds__(256) void rasterize(
    const float* __restrict__ coef, const unsigned int* __restrict__ bbox,
    float* __restrict__ out)
{
    __shared__ float cl[TPC * CPT];          // 12 KB worst case
    __shared__ unsigned short s_list[256];
    __shared__ int s_n, wbase[4];

    const int blk   = blockIdx.x;
    const int b     = blk >> 10;
    const int rest  = blk & 1023;
    const int chunk = rest & (NCHK - 1);     // chunk-major: heavy tiles spread
    const int tile  = rest >> 2;             // 16x16 tiles of 16x16 px
    const int tx0   = (tile >> 4) << 4;
    const int ty0   = (tile & 15) << 4;

    const int l  = threadIdx.x & 63;
    const int wv = threadIdx.x >> 6;

    if (threadIdx.x == 0) s_n = 0;
    __syncthreads();

    const int base = chunk * TPC;
    const int t = threadIdx.x;
    bool hit = false;
    if (t < TPC) {
        const unsigned int w = bbox[(size_t)b * NTRI + base + t];
        const int tbx0 = w & 255, tbx1 = (w >> 8) & 255;
        const int tby0 = (w >> 16) & 255, tby1 = w >> 24;
        hit = !(tbx1 < tx0 || tbx0 > tx0 + 15 || tby1 < ty0 || tby0 > ty0 + 15);
    }
    const unsigned long long m = __ballot(hit);
    if (l == 0) wbase[wv] = atomicAdd(&s_n, (int)__popcll(m));
    __syncthreads();
    if (hit) {
        const int pos = wbase[wv] + (int)__popcll(m & ((1ull << l) - 1ull));
        s_list[pos] = (unsigned short)t;
    }
    __syncthreads();
    const int n = s_n;

    {
        const float* cb = coef + ((size_t)b * NTRI + base) * CPT;
        for (int j = threadIdx.x; j < n * CPT; j += 256) {
            const int k = j / CPT, w = j - k * CPT;
            cl[j] = cb[(int)s_list[k] * CPT + w];
        }
    }
    __syncthreads();

    const int px = tx0 + (threadIdx.x >> 4);
    const int py = ty0 + (threadIdx.x & 15);
    const float fx = (float)px, fy = (float)py;

    float acc = 0.0f;
#pragma unroll 2
    for (int k = 0; k < n; ++k) {
        const float* r = &cl[k * CPT];
        const float u1 = fmaxf(fmaf(r[0], fx, fmaf(r[1], fy, r[2])), 0.0f);
        const float u2 = fmaxf(fmaf(r[3], fx, fmaf(r[4], fy, r[5])), 0.0f);
        const float u3 = fmaxf(fmaf(r[6], fx, fmaf(r[7], fy, r[8])), 0.0f);
        const float e  = __builtin_amdgcn_exp2f(fmaf(u1*u2*u3, r[9], -r[10]));
        acc += __builtin_amdgcn_rcpf(1.0f + e);
    }

    const float v = fmaf(-2.0f, acc, (float)n);
    atomicAdd(out + (size_t)b * NPIX + (size_t)px * RES + py, v);
}

extern "C" void kernel_launch(void* const* d_in, const int* in_sizes, int n_in,
                              void* d_out, int out_size, void* d_ws, size_t ws_size,
                              hipStream_t stream)
{
    const float* meshes = (const float*)d_in[0];
    const float* Km     = (const float*)d_in[1];
    const int*   midx   = (const int*)d_in[2];
    const float* cams   = (const float*)d_in[3];
    float* out = (float*)d_out;

    const int batch = in_sizes[3] / 12;     // camera_poses is (B,3,4)

    float* coef = (float*)d_ws;                               // batch*1000*12 f32
    unsigned int* bbox =
        (unsigned int*)((char*)d_ws + (size_t)batch * NTRI * CPT * sizeof(float));

    tri_setup<<<dim3(batch * NTRI), dim3(256), 0, stream>>>(
        meshes, Km, midx, cams, coef, bbox, out, batch * NPIX);
    rasterize<<<dim3(batch * 256 * NCHK), dim3(256), 0, stream>>>(coef, bbox, out);
}